// Round 9
// baseline (148.289 us; speedup 1.0000x reference)
//
#include <hip/hip_runtime.h>
#include <hip/hip_fp16.h>
#include <stdint.h>

// MaskCrossAttention: B=4, LQ=LKV=1024, C=EMBED=768, NH=12, HD=64, SCALE=0.125
// Round 8: r7 (all-coalesced staging) with the pos-stage OOB fixed:
// pos tile is 64 rows x 32 f32 = 8KB = 512 chunks -> stage loop k<2 (was k<4,
// read rows 64..127 past the pos buffer -> memory fault). stage = 4
// gload_lds/thread -> vmcnt(4). LDS 32KB.

typedef _Float16 f16;
typedef __attribute__((ext_vector_type(8))) _Float16 f16x8;
typedef __attribute__((ext_vector_type(4))) _Float16 f16x4;
typedef __attribute__((ext_vector_type(4))) float f32x4;

__device__ __forceinline__ void gload16(const void* g, void* l) {
  __builtin_amdgcn_global_load_lds(
      (__attribute__((address_space(1))) void*)(uintptr_t)g,
      (__attribute__((address_space(3))) void*)(uint32_t)(uintptr_t)l,
      16, 0, 0);
}

// ---------------- fused prep: cvt Xq, cvt Xkv, transpose Wq/Wkv/Wp ----------
__device__ __forceinline__ void cvt4_job(const float* __restrict__ in,
                                         f16* __restrict__ out, int i) {
  float4 v = reinterpret_cast<const float4*>(in)[i];
  f16x4 o = {(f16)v.x, (f16)v.y, (f16)v.z, (f16)v.w};
  reinterpret_cast<f16x4*>(out)[i] = o;
}
__device__ __forceinline__ void transw_job(const float* __restrict__ W,
                                           f16* __restrict__ Wt, int N, int bid,
                                           int tid) {
  int kcb = bid % 96;  // 96 = 768/8
  int n = (bid / 96) * 256 + tid;
  int k0 = kcb * 8;
  f16x8 o;
#pragma unroll
  for (int j = 0; j < 8; ++j) o[j] = (f16)W[(size_t)(k0 + j) * N + n];
  *reinterpret_cast<f16x8*>(Wt + (size_t)n * 768 + k0) = o;
}
__global__ __launch_bounds__(256) void prep_kernel(
    const float* __restrict__ Xq, const float* __restrict__ Xkv,
    const float* __restrict__ Wq, const float* __restrict__ Wkv,
    const float* __restrict__ Wp, f16* __restrict__ Xq_h,
    f16* __restrict__ Xkv_h, f16* __restrict__ WqT, f16* __restrict__ WkvT,
    f16* __restrict__ WpT) {
  const int bid = blockIdx.x, tid = threadIdx.x;
  if (bid < 3072) cvt4_job(Xq, Xq_h, bid * 256 + tid);
  else if (bid < 6144) cvt4_job(Xkv, Xkv_h, (bid - 3072) * 256 + tid);
  else if (bid < 6432) transw_job(Wq, WqT, 768, bid - 6144, tid);
  else if (bid < 7008) transw_job(Wkv, WkvT, 1536, bid - 6432, tid);
  else transw_job(Wp, WpT, 768, bid - 7008, tid);
}

// ---------------- GEMM body: C = A(4096x768) * Bt(N x 768)^T + bias ---------
template <int NDIM, int EPI>
__device__ __forceinline__ void gemm_body(int bid, f16* As, f16* Bs,
                                          const f16* __restrict__ A,
                                          const f16* __restrict__ Bt,
                                          const float* __restrict__ bias,
                                          void* __restrict__ out0,
                                          void* __restrict__ out1) {
  constexpr int KD = 768;
  const int t = threadIdx.x;
  const int lane = t & 63, wid = t >> 6;
  const int bm = bid / (NDIM / 128), bn = bid % (NDIM / 128);
  const int m0 = bm * 128, n0 = bn * 128;
  const int wm = wid >> 1, wn = wid & 1;
  const int cr = lane & 15, grp = lane >> 4;
  f32x4 acc[4][4] = {};
  for (int k0 = 0; k0 < KD; k0 += 32) {
    __syncthreads();
#pragma unroll
    for (int it = 0; it < 2; ++it) {
      int ia = it * 256 + wid * 64 + lane;
      int kc = ia >> 7, row = ia & 127;
      gload16(A + (size_t)(m0 + row) * KD + k0 + kc * 8,
              As + (it * 256 + wid * 64) * 8);
      gload16(Bt + (size_t)(n0 + row) * KD + k0 + kc * 8,
              Bs + (it * 256 + wid * 64) * 8);
    }
    __syncthreads();
    f16x8 af[4], bf[4];
#pragma unroll
    for (int mf = 0; mf < 4; ++mf)
      af[mf] = *reinterpret_cast<const f16x8*>(As + (grp * 128 + wm * 64 + mf * 16 + cr) * 8);
#pragma unroll
    for (int nf = 0; nf < 4; ++nf)
      bf[nf] = *reinterpret_cast<const f16x8*>(Bs + (grp * 128 + wn * 64 + nf * 16 + cr) * 8);
#pragma unroll
    for (int mf = 0; mf < 4; ++mf)
#pragma unroll
      for (int nf = 0; nf < 4; ++nf)
        acc[mf][nf] = __builtin_amdgcn_mfma_f32_16x16x32_f16(af[mf], bf[nf], acc[mf][nf], 0, 0, 0);
  }
#pragma unroll
  for (int mf = 0; mf < 4; ++mf) {
    int m = m0 + wm * 64 + mf * 16 + grp * 4;  // +r per reg
    int b = m >> 10, lrow = m & 1023;
#pragma unroll
    for (int nf = 0; nf < 4; ++nf) {
      int n = n0 + wn * 64 + nf * 16 + cr;
      float bv = bias[n];
      f32x4 v = acc[mf][nf];
      if constexpr (EPI == 0) {
        int h = n >> 6, d = n & 63;
        f16* dst = (f16*)out0 + (((size_t)b * 12 + h) * 1024 + lrow) * 64 + d;
#pragma unroll
        for (int r = 0; r < 4; ++r) dst[(size_t)r * 64] = (f16)((v[r] + bv) * 0.125f);
      } else if constexpr (EPI == 1) {
        if (n < 768) {
          int h = n >> 6, d = n & 63;
          f16* dst = (f16*)out0 + (((size_t)b * 12 + h) * 1024 + lrow) * 64 + d;
#pragma unroll
          for (int r = 0; r < 4; ++r) dst[(size_t)r * 64] = (f16)(v[r] + bv);
        } else {
          int n2 = n - 768;
          int h = n2 >> 6, d = n2 & 63;
          f16x4 o;
#pragma unroll
          for (int r = 0; r < 4; ++r) o[r] = (f16)(v[r] + bv);
          *reinterpret_cast<f16x4*>((f16*)out1 + (((size_t)b * 12 + h) * 64 + d) * 1024 + lrow) = o;
        }
      } else {
        float* dst = (float*)out0 + (size_t)m * 768 + n;
#pragma unroll
        for (int r = 0; r < 4; ++r) dst[(size_t)r * 768] = v[r] + bv;
      }
    }
  }
}

__global__ __launch_bounds__(256) void gemm_qkv_kernel(
    const f16* __restrict__ Xq_h, const f16* __restrict__ WqT,
    const float* __restrict__ bq, f16* __restrict__ Qb,
    const f16* __restrict__ Xkv_h, const f16* __restrict__ WkvT,
    const float* __restrict__ bkv, f16* __restrict__ Kb, f16* __restrict__ VTb) {
  __shared__ f16 As[4096];
  __shared__ f16 Bs[4096];
  const int swz = (blockIdx.x % 8) * 72 + blockIdx.x / 8;  // 576 = 8*72
  if (swz < 192)
    gemm_body<768, 0>(swz, As, Bs, Xq_h, WqT, bq, Qb, nullptr);
  else
    gemm_body<1536, 1>(swz - 192, As, Bs, Xkv_h, WkvT, bkv, Kb, VTb);
}

__global__ __launch_bounds__(256) void gemm_out_kernel(
    const f16* __restrict__ attO, const f16* __restrict__ WpT,
    const float* __restrict__ bp, float* __restrict__ out) {
  __shared__ f16 As[4096];
  __shared__ f16 Bs[4096];
  const int swz = (blockIdx.x % 8) * 24 + blockIdx.x / 8;  // 192 = 8*24
  gemm_body<768, 2>(swz, As, Bs, attO, WpT, bp, out, nullptr);
}

// ---------------- fused flash attention: all-coalesced staging -------------
// 768 blocks x 256 threads (4 waves x 16 q-rows), KVBLK=32, 32 tiles,
// double-buffered named LDS (A/B), 4 gload_lds/thread/tile, vmcnt(4).
// LDS layouts (16B-chunk XOR-swizzle; linear dest + inverse-swizzled source
// + swizzled read per rule #21):
//   K  [kv32][c8][8f16]  slot kv*8 + (g^(kv&7))   (4 KB)
//   V  [d64][kvc4][8f16] plain                    (4 KB)
//   pos[q64][c8][4f32]   slot qr*8 + (g^(qr&7))   (8 KB)
// Block remap: 4 batches of one (h,qtile) adjacent on one XCD (pos L2-shared).
__global__ __launch_bounds__(256, 3) void attn_kernel(
    const f16* __restrict__ Q, const f16* __restrict__ K,
    const f16* __restrict__ VT, const float* __restrict__ pos,
    const float* __restrict__ mask, f16* __restrict__ attO) {
  __shared__ f16 KsA[2048], KsB[2048];   // [kv32][c8][8 f16]
  __shared__ f16 VsA[2048], VsB[2048];   // [d64][kvc4][8 f16]
  __shared__ float PsA[2048], PsB[2048]; // [q64][c8][4 f32]
  const int t = threadIdx.x;
  const int lane = t & 63, wid = t >> 6;
  const int xcd = blockIdx.x & 7;
  const int j = blockIdx.x >> 3;            // 0..95
  const int gidx = xcd * 24 + (j >> 2);     // 0..191 = h*16 + qtile
  const int b = j & 3;
  const int h = gidx >> 4;
  const int qt = gidx & 15;
  const int bh = b * 12 + h;
  const int cq = lane & 15, grp = lane >> 4;
  const int q = qt * 64 + wid * 16 + cq;
  const f16* Qp = Q + ((size_t)bh * 1024 + q) * 64 + grp * 8;
  const f16x8 qf0 = *reinterpret_cast<const f16x8*>(Qp);
  const f16x8 qf1 = *reinterpret_cast<const f16x8*>(Qp + 32);
  const f16* Kb = K + (size_t)bh * 65536;
  const f16* Vb = VT + (size_t)bh * 65536;
  const float* pblk = pos + ((size_t)h * 1024 + qt * 64) * 1024;

  float m_run = -1e30f, l_run = 0.f;
  f32x4 acc[4] = {};  // O^T: acc[df][r] -> d = df*16 + grp*4 + r, col q

  // staging indices (all consecutive-lane within one or two cache lines)
  const int skv = t >> 3, skc = (t & 7) ^ ((t >> 3) & 7);  // K
  const int svd = t >> 2, svc = t & 3;                     // V
  const int pqr0 = t >> 3, pc0 = (t & 7) ^ ((t >> 3) & 7);          // pos k=0
  const int pqr1 = (256 + t) >> 3, pc1 = (t & 7) ^ (((256 + t) >> 3) & 7);
  auto stage = [&](f16* Ksb, f16* Vsb, float* Psb, int kv0) {
    gload16(Kb + (size_t)(kv0 + skv) * 64 + skc * 8, Ksb + t * 8);
    gload16(Vb + (size_t)svd * 1024 + kv0 + svc * 8, Vsb + t * 8);
    gload16(pblk + (size_t)pqr0 * 1024 + kv0 + pc0 * 4, Psb + t * 4);
    gload16(pblk + (size_t)pqr1 * 1024 + kv0 + pc1 * 4, Psb + (256 + t) * 4);
  };

  const int swc = cq & 7;  // read-side swizzle key (row&7 == cq&7)
  auto compute = [&](const f16* Ksb, const f16* Vsb, const float* Psb) {
    f32x4 st[2];
    __builtin_amdgcn_s_setprio(1);
#pragma unroll
    for (int f = 0; f < 2; ++f) {
      f16x8 kf0 = *reinterpret_cast<const f16x8*>(
          Ksb + ((f * 16 + cq) * 8 + (grp ^ swc)) * 8);
      f16x8 kf1 = *reinterpret_cast<const f16x8*>(
          Ksb + ((f * 16 + cq) * 8 + ((4 + grp) ^ swc)) * 8);
      f32x4 z = {0.f, 0.f, 0.f, 0.f};
      z = __builtin_amdgcn_mfma_f32_16x16x32_f16(kf0, qf0, z, 0, 0, 0);
      z = __builtin_amdgcn_mfma_f32_16x16x32_f16(kf1, qf1, z, 0, 0, 0);
      st[f] = z + *reinterpret_cast<const f32x4*>(
                      Psb + ((wid * 16 + cq) * 8 + ((f * 4 + grp) ^ swc)) * 4);
    }
    __builtin_amdgcn_s_setprio(0);
    float tm = -1e30f;
#pragma unroll
    for (int f = 0; f < 2; ++f)
#pragma unroll
      for (int r = 0; r < 4; ++r) tm = fmaxf(tm, st[f][r]);
    tm = fmaxf(tm, __shfl_xor(tm, 16));
    tm = fmaxf(tm, __shfl_xor(tm, 32));
    if (!__all(tm <= m_run + 8.f)) {  // T13 defer-rescale
      const float m_new = fmaxf(m_run, tm);
      const float corr = __expf(m_run - m_new);
      l_run *= corr;
#pragma unroll
      for (int df = 0; df < 4; ++df) acc[df] *= corr;
      m_run = m_new;
    }
    float ls = 0.f;
    f16x4 pf[2];
#pragma unroll
    for (int f = 0; f < 2; ++f)
#pragma unroll
      for (int r = 0; r < 4; ++r) {
        float p = __expf(st[f][r] - m_run);
        ls += p;
        pf[f][r] = (f16)p;
      }
    ls += __shfl_xor(ls, 16);
    ls += __shfl_xor(ls, 32);
    l_run += ls;
    __builtin_amdgcn_s_setprio(1);
#pragma unroll
    for (int f = 0; f < 2; ++f)
#pragma unroll
      for (int df = 0; df < 4; ++df) {
        f16x4 vf = *reinterpret_cast<const f16x4*>(
            Vsb + (df * 16 + cq) * 32 + (f * 2 + (grp >> 1)) * 8 + (grp & 1) * 4);
        acc[df] = __builtin_amdgcn_mfma_f32_16x16x16f16(vf, pf[f], acc[df], 0, 0, 0);
      }
    __builtin_amdgcn_s_setprio(0);
  };

  stage(KsA, VsA, PsA, 0);
  asm volatile("" ::: "memory");
  for (int te = 0; te < 32; te += 2) {
    stage(KsB, VsB, PsB, (te + 1) * 32);
    asm volatile("" ::: "memory");
    asm volatile("s_waitcnt vmcnt(4)" ::: "memory");
    __builtin_amdgcn_s_barrier();
    compute(KsA, VsA, PsA);
    __builtin_amdgcn_s_barrier();
    if (te + 2 < 32) {
      stage(KsA, VsA, PsA, (te + 2) * 32);
      asm volatile("" ::: "memory");
      asm volatile("s_waitcnt vmcnt(4)" ::: "memory");
    } else {
      asm volatile("s_waitcnt vmcnt(0)" ::: "memory");
    }
    __builtin_amdgcn_s_barrier();
    compute(KsB, VsB, PsB);
    if (te + 2 < 32) __builtin_amdgcn_s_barrier();
  }

  const float sc = mask[b * 1024 + q] / l_run;
  f16* ob = attO + ((size_t)b * 1024 + q) * 768 + h * 64;
#pragma unroll
  for (int df = 0; df < 4; ++df) {
    f16x4 o;
#pragma unroll
    for (int r = 0; r < 4; ++r) o[r] = (f16)(acc[df][r] * sc);
    *reinterpret_cast<f16x4*>(ob + df * 16 + grp * 4) = o;
  }
}

extern "C" void kernel_launch(void* const* d_in, const int* in_sizes, int n_in,
                              void* d_out, int out_size, void* d_ws, size_t ws_size,
                              hipStream_t stream) {
  const float* Xq   = (const float*)d_in[0];
  const float* Xkv  = (const float*)d_in[1];
  const float* mask = (const float*)d_in[2];
  const float* Wq   = (const float*)d_in[3];
  const float* bq   = (const float*)d_in[4];
  const float* Wkv  = (const float*)d_in[5];
  const float* bkv  = (const float*)d_in[6];
  const float* Wp   = (const float*)d_in[7];
  const float* bp   = (const float*)d_in[8];
  const float* pos  = (const float*)d_in[9];
  float* out = (float*)d_out;
  char* ws = (char*)d_ws;
  if (ws_size < 42467328) return;  // need ~42.5 MB scratch

  f16* Xq_h  = (f16*)(ws + 0);         // 4096*768
  f16* Xkv_h = (f16*)(ws + 6291456);   // 4096*768
  f16* WqT   = (f16*)(ws + 12582912);  // 768*768
  f16* WkvT  = (f16*)(ws + 13762560);  // 1536*768
  f16* WpT   = (f16*)(ws + 16121856);  // 768*768
  f16* Qb    = (f16*)(ws + 17301504);  // (B,NH,LQ,HD)
  f16* Kb    = (f16*)(ws + 23592960);  // (B,NH,LKV,HD)
  f16* VTb   = (f16*)(ws + 29884416);  // (B,NH,HD,LKV)
  f16* attO  = (f16*)(ws + 36175872);  // (B,LQ,EMBED)

  prep_kernel<<<7296, 256, 0, stream>>>(Xq, Xkv, Wq, Wkv, Wp, Xq_h, Xkv_h, WqT,
                                        WkvT, WpT);
  gemm_qkv_kernel<<<576, 256, 0, stream>>>(Xq_h, WqT, bq, Qb, Xkv_h, WkvT, bkv,
                                           Kb, VTb);
  attn_kernel<<<768, 256, 0, stream>>>(Qb, Kb, VTb, pos, mask, attO);
  gemm_out_kernel<<<192, 256, 0, stream>>>(attO, WpT, bp, out);
}

// Round 10
// 134.832 us; speedup vs baseline: 1.0998x; 1.0998x over previous
//
#include <hip/hip_runtime.h>
#include <hip/hip_fp16.h>
#include <stdint.h>

// MaskCrossAttention: B=4, LQ=LKV=1024, C=EMBED=768, NH=12, HD=64, SCALE=0.125
// Round 9: attn = T15 double-pipeline. Each window runs phase A (QK^T+pos,
// tile t) and phase B (softmax+PV, tile t-1) back-to-back as independent
// chains so the SIMD always has issueable work. KVBLK=32, 5 K/V LDS buffers
// (40KB -> 4 blocks/CU), pos in regs 2 windows ahead, st double-buffered.
// Layouts identical to r5/r6 (passed); only the schedule is new.

typedef _Float16 f16;
typedef __attribute__((ext_vector_type(8))) _Float16 f16x8;
typedef __attribute__((ext_vector_type(4))) _Float16 f16x4;
typedef __attribute__((ext_vector_type(4))) float f32x4;

__device__ __forceinline__ void gload16(const void* g, void* l) {
  __builtin_amdgcn_global_load_lds(
      (__attribute__((address_space(1))) void*)(uintptr_t)g,
      (__attribute__((address_space(3))) void*)(uint32_t)(uintptr_t)l,
      16, 0, 0);
}

// ---------------- fused prep: cvt Xq, cvt Xkv, transpose Wq/Wkv/Wp ----------
__device__ __forceinline__ void cvt4_job(const float* __restrict__ in,
                                         f16* __restrict__ out, int i) {
  float4 v = reinterpret_cast<const float4*>(in)[i];
  f16x4 o = {(f16)v.x, (f16)v.y, (f16)v.z, (f16)v.w};
  reinterpret_cast<f16x4*>(out)[i] = o;
}
__device__ __forceinline__ void transw_job(const float* __restrict__ W,
                                           f16* __restrict__ Wt, int N, int bid,
                                           int tid) {
  int kcb = bid % 96;  // 96 = 768/8
  int n = (bid / 96) * 256 + tid;
  int k0 = kcb * 8;
  f16x8 o;
#pragma unroll
  for (int j = 0; j < 8; ++j) o[j] = (f16)W[(size_t)(k0 + j) * N + n];
  *reinterpret_cast<f16x8*>(Wt + (size_t)n * 768 + k0) = o;
}
__global__ __launch_bounds__(256) void prep_kernel(
    const float* __restrict__ Xq, const float* __restrict__ Xkv,
    const float* __restrict__ Wq, const float* __restrict__ Wkv,
    const float* __restrict__ Wp, f16* __restrict__ Xq_h,
    f16* __restrict__ Xkv_h, f16* __restrict__ WqT, f16* __restrict__ WkvT,
    f16* __restrict__ WpT) {
  const int bid = blockIdx.x, tid = threadIdx.x;
  if (bid < 3072) cvt4_job(Xq, Xq_h, bid * 256 + tid);
  else if (bid < 6144) cvt4_job(Xkv, Xkv_h, (bid - 3072) * 256 + tid);
  else if (bid < 6432) transw_job(Wq, WqT, 768, bid - 6144, tid);
  else if (bid < 7008) transw_job(Wkv, WkvT, 1536, bid - 6432, tid);
  else transw_job(Wp, WpT, 768, bid - 7008, tid);
}

// ---------------- GEMM body: C = A(4096x768) * Bt(N x 768)^T + bias ---------
template <int NDIM, int EPI>
__device__ __forceinline__ void gemm_body(int bid, f16* As, f16* Bs,
                                          const f16* __restrict__ A,
                                          const f16* __restrict__ Bt,
                                          const float* __restrict__ bias,
                                          void* __restrict__ out0,
                                          void* __restrict__ out1) {
  constexpr int KD = 768;
  const int t = threadIdx.x;
  const int lane = t & 63, wid = t >> 6;
  const int bm = bid / (NDIM / 128), bn = bid % (NDIM / 128);
  const int m0 = bm * 128, n0 = bn * 128;
  const int wm = wid >> 1, wn = wid & 1;
  const int cr = lane & 15, grp = lane >> 4;
  f32x4 acc[4][4] = {};
  for (int k0 = 0; k0 < KD; k0 += 32) {
    __syncthreads();
#pragma unroll
    for (int it = 0; it < 2; ++it) {
      int ia = it * 256 + wid * 64 + lane;
      int kc = ia >> 7, row = ia & 127;
      gload16(A + (size_t)(m0 + row) * KD + k0 + kc * 8,
              As + (it * 256 + wid * 64) * 8);
      gload16(Bt + (size_t)(n0 + row) * KD + k0 + kc * 8,
              Bs + (it * 256 + wid * 64) * 8);
    }
    __syncthreads();
    f16x8 af[4], bf[4];
#pragma unroll
    for (int mf = 0; mf < 4; ++mf)
      af[mf] = *reinterpret_cast<const f16x8*>(As + (grp * 128 + wm * 64 + mf * 16 + cr) * 8);
#pragma unroll
    for (int nf = 0; nf < 4; ++nf)
      bf[nf] = *reinterpret_cast<const f16x8*>(Bs + (grp * 128 + wn * 64 + nf * 16 + cr) * 8);
#pragma unroll
    for (int mf = 0; mf < 4; ++mf)
#pragma unroll
      for (int nf = 0; nf < 4; ++nf)
        acc[mf][nf] = __builtin_amdgcn_mfma_f32_16x16x32_f16(af[mf], bf[nf], acc[mf][nf], 0, 0, 0);
  }
#pragma unroll
  for (int mf = 0; mf < 4; ++mf) {
    int m = m0 + wm * 64 + mf * 16 + grp * 4;  // +r per reg
    int b = m >> 10, lrow = m & 1023;
#pragma unroll
    for (int nf = 0; nf < 4; ++nf) {
      int n = n0 + wn * 64 + nf * 16 + cr;
      float bv = bias[n];
      f32x4 v = acc[mf][nf];
      if constexpr (EPI == 0) {
        int h = n >> 6, d = n & 63;
        f16* dst = (f16*)out0 + (((size_t)b * 12 + h) * 1024 + lrow) * 64 + d;
#pragma unroll
        for (int r = 0; r < 4; ++r) dst[(size_t)r * 64] = (f16)((v[r] + bv) * 0.125f);
      } else if constexpr (EPI == 1) {
        if (n < 768) {
          int h = n >> 6, d = n & 63;
          f16* dst = (f16*)out0 + (((size_t)b * 12 + h) * 1024 + lrow) * 64 + d;
#pragma unroll
          for (int r = 0; r < 4; ++r) dst[(size_t)r * 64] = (f16)(v[r] + bv);
        } else {
          int n2 = n - 768;
          int h = n2 >> 6, d = n2 & 63;
          f16x4 o;
#pragma unroll
          for (int r = 0; r < 4; ++r) o[r] = (f16)(v[r] + bv);
          *reinterpret_cast<f16x4*>((f16*)out1 + (((size_t)b * 12 + h) * 64 + d) * 1024 + lrow) = o;
        }
      } else {
        float* dst = (float*)out0 + (size_t)m * 768 + n;
#pragma unroll
        for (int r = 0; r < 4; ++r) dst[(size_t)r * 768] = v[r] + bv;
      }
    }
  }
}

__global__ __launch_bounds__(256) void gemm_qkv_kernel(
    const f16* __restrict__ Xq_h, const f16* __restrict__ WqT,
    const float* __restrict__ bq, f16* __restrict__ Qb,
    const f16* __restrict__ Xkv_h, const f16* __restrict__ WkvT,
    const float* __restrict__ bkv, f16* __restrict__ Kb, f16* __restrict__ VTb) {
  __shared__ f16 As[4096];
  __shared__ f16 Bs[4096];
  const int swz = (blockIdx.x % 8) * 72 + blockIdx.x / 8;  // 576 = 8*72
  if (swz < 192)
    gemm_body<768, 0>(swz, As, Bs, Xq_h, WqT, bq, Qb, nullptr);
  else
    gemm_body<1536, 1>(swz - 192, As, Bs, Xkv_h, WkvT, bkv, Kb, VTb);
}

__global__ __launch_bounds__(256) void gemm_out_kernel(
    const f16* __restrict__ attO, const f16* __restrict__ WpT,
    const float* __restrict__ bp, float* __restrict__ out) {
  __shared__ f16 As[4096];
  __shared__ f16 Bs[4096];
  const int swz = (blockIdx.x % 8) * 24 + blockIdx.x / 8;  // 192 = 8*24
  gemm_body<768, 2>(swz, As, Bs, attO, WpT, bp, out, nullptr);
}

// ---------------- fused flash attention: A||B double-pipeline --------------
// 768 blocks x 256 threads (4 waves x 16 q-rows). KVBLK=32, 33 windows.
// Window T: stage(T+3) -> vmcnt -> barrier -> phaseA(QK^T tile T, writes stN)
// || phaseB(softmax+PV tile T-1, reads stP) -> loadpos(T+2) -> barrier.
// 5 K/V LDS buffers (rotation period 5; overwrite target is 4 tiles stale).
// Block remap: 4 batches of one (h,qtile) adjacent on one XCD (pos L2-shared).
__global__ __launch_bounds__(256, 4) void attn_kernel(
    const f16* __restrict__ Q, const f16* __restrict__ K,
    const f16* __restrict__ VT, const float* __restrict__ pos,
    const float* __restrict__ mask, f16* __restrict__ attO) {
  __shared__ f16 Ks0[2048], Ks1[2048], Ks2[2048], Ks3[2048], Ks4[2048];
  __shared__ f16 Vs0[2048], Vs1[2048], Vs2[2048], Vs3[2048], Vs4[2048];
  const int t = threadIdx.x;
  const int lane = t & 63, wid = t >> 6;
  const int xcd = blockIdx.x & 7;
  const int j = blockIdx.x >> 3;            // 0..95
  const int gidx = xcd * 24 + (j >> 2);     // 0..191 = h*16 + qtile
  const int b = j & 3;
  const int h = gidx >> 4;
  const int qt = gidx & 15;
  const int bh = b * 12 + h;
  const int cq = lane & 15, grp = lane >> 4;
  const int q = qt * 64 + wid * 16 + cq;
  const f16* Qp = Q + ((size_t)bh * 1024 + q) * 64 + grp * 8;
  const f16x8 qf0 = *reinterpret_cast<const f16x8*>(Qp);
  const f16x8 qf1 = *reinterpret_cast<const f16x8*>(Qp + 32);
  const f16* Kb = K + (size_t)bh * 65536;
  const f16* Vb = VT + (size_t)bh * 65536;
  const float* pb = pos + ((size_t)h * 1024 + q) * 1024;

  float m_run = -1e30f, l_run = 0.f;
  f32x4 acc[4] = {};  // O^T: acc[df][r] -> d = df*16 + grp*4 + r, col q
  f32x4 psA[2], psB[2];  // pos frags, parity T&1
  f32x4 stA[2], stB[2];  // QK^T+pos scores, parity T&1

  const int sdc = t >> 5, skv = t & 31;  // K stage: [dc(8)][kv(32)][8]
  const int shi = t >> 6, slo = t & 63;  // V stage: [kc4(4)][d(64)][8]
  auto stageKV = [&](f16* Ksb, f16* Vsb, int kv0) {
    gload16(Kb + (size_t)(kv0 + skv) * 64 + sdc * 8, Ksb + t * 8);
    gload16(Vb + (size_t)slo * 1024 + kv0 + shi * 8, Vsb + t * 8);
  };
  auto loadpos = [&](f32x4* psX, int kv0) {
    psX[0] = *reinterpret_cast<const f32x4*>(pb + kv0 + grp * 4);
    psX[1] = *reinterpret_cast<const f32x4*>(pb + kv0 + 16 + grp * 4);
  };
  // phase A: QK^T of the current tile into stN (pure MFMA + adds)
  auto phaseA = [&](const f16* Ksb, const f32x4* psX, f32x4* stN) {
    __builtin_amdgcn_s_setprio(1);
#pragma unroll
    for (int f = 0; f < 2; ++f) {
      f16x8 kf0 = *reinterpret_cast<const f16x8*>(Ksb + (grp * 32 + f * 16 + cq) * 8);
      f16x8 kf1 = *reinterpret_cast<const f16x8*>(Ksb + ((4 + grp) * 32 + f * 16 + cq) * 8);
      f32x4 z = {0.f, 0.f, 0.f, 0.f};
      z = __builtin_amdgcn_mfma_f32_16x16x32_f16(kf0, qf0, z, 0, 0, 0);
      z = __builtin_amdgcn_mfma_f32_16x16x32_f16(kf1, qf1, z, 0, 0, 0);
      stN[f] = z + psX[f];
    }
    __builtin_amdgcn_s_setprio(0);
  };
  // phase B: softmax + PV of the previous tile from stP
  auto phaseB = [&](const f16* Vsb, const f32x4* stP) {
    float tm = -1e30f;
#pragma unroll
    for (int f = 0; f < 2; ++f)
#pragma unroll
      for (int r = 0; r < 4; ++r) tm = fmaxf(tm, stP[f][r]);
    tm = fmaxf(tm, __shfl_xor(tm, 16));
    tm = fmaxf(tm, __shfl_xor(tm, 32));
    if (!__all(tm <= m_run + 8.f)) {  // T13 defer-rescale
      const float m_new = fmaxf(m_run, tm);
      const float corr = __expf(m_run - m_new);
      l_run *= corr;
#pragma unroll
      for (int df = 0; df < 4; ++df) acc[df] *= corr;
      m_run = m_new;
    }
    float ls = 0.f;
    f16x4 pf[2];
#pragma unroll
    for (int f = 0; f < 2; ++f)
#pragma unroll
      for (int r = 0; r < 4; ++r) {
        float p = __expf(stP[f][r] - m_run);
        ls += p;
        pf[f][r] = (f16)p;
      }
    ls += __shfl_xor(ls, 16);
    ls += __shfl_xor(ls, 32);
    l_run += ls;
    __builtin_amdgcn_s_setprio(1);
#pragma unroll
    for (int f = 0; f < 2; ++f)
#pragma unroll
      for (int df = 0; df < 4; ++df) {
        f16x4 vf = *reinterpret_cast<const f16x4*>(
            Vsb + ((f * 2 + (grp >> 1)) * 64 + df * 16 + cq) * 8 + (grp & 1) * 4);
        acc[df] = __builtin_amdgcn_mfma_f32_16x16x16f16(vf, pf[f], acc[df], 0, 0, 0);
      }
    __builtin_amdgcn_s_setprio(0);
  };

  // prologue: stage tiles 0..2, pos 0..1 (order matters for vmcnt constants)
  stageKV(Ks0, Vs0, 0);
  loadpos(psA, 0);
  asm volatile("" ::: "memory");
  stageKV(Ks1, Vs1, 32);
  loadpos(psB, 32);
  asm volatile("" ::: "memory");
  stageKV(Ks2, Vs2, 64);
  asm volatile("" ::: "memory");

#define WSTEP(T, KC, VP, SK, SV, PSX, STN, STP, VM)                     \
  {                                                                     \
    if ((T) + 3 < 32) stageKV(SK, SV, ((T) + 3) * 32);                  \
    asm volatile("" ::: "memory");                                      \
    asm volatile("s_waitcnt vmcnt(" #VM ")" ::: "memory");              \
    __builtin_amdgcn_s_barrier();                                       \
    if ((T) < 32) phaseA(KC, PSX, STN);                                 \
    if ((T) > 0) phaseB(VP, STP);                                       \
    if ((T) + 2 < 32) loadpos(PSX, ((T) + 2) * 32);                     \
    asm volatile("" ::: "memory");                                      \
    if ((T) < 32) __builtin_amdgcn_s_barrier();                         \
  }

  WSTEP(0,  Ks0, Vs0, Ks3, Vs3, psA, stA, stB, 14)
  WSTEP(1,  Ks1, Vs0, Ks4, Vs4, psB, stB, stA, 14)
  WSTEP(2,  Ks2, Vs1, Ks0, Vs0, psA, stA, stB, 10)
  WSTEP(3,  Ks3, Vs2, Ks1, Vs1, psB, stB, stA, 10)
  WSTEP(4,  Ks4, Vs3, Ks2, Vs2, psA, stA, stB, 10)
  WSTEP(5,  Ks0, Vs4, Ks3, Vs3, psB, stB, stA, 10)
  WSTEP(6,  Ks1, Vs0, Ks4, Vs4, psA, stA, stB, 10)
  WSTEP(7,  Ks2, Vs1, Ks0, Vs0, psB, stB, stA, 10)
  WSTEP(8,  Ks3, Vs2, Ks1, Vs1, psA, stA, stB, 10)
  WSTEP(9,  Ks4, Vs3, Ks2, Vs2, psB, stB, stA, 10)
  WSTEP(10, Ks0, Vs4, Ks3, Vs3, psA, stA, stB, 10)
  WSTEP(11, Ks1, Vs0, Ks4, Vs4, psB, stB, stA, 10)
  WSTEP(12, Ks2, Vs1, Ks0, Vs0, psA, stA, stB, 10)
  WSTEP(13, Ks3, Vs2, Ks1, Vs1, psB, stB, stA, 10)
  WSTEP(14, Ks4, Vs3, Ks2, Vs2, psA, stA, stB, 10)
  WSTEP(15, Ks0, Vs4, Ks3, Vs3, psB, stB, stA, 10)
  WSTEP(16, Ks1, Vs0, Ks4, Vs4, psA, stA, stB, 10)
  WSTEP(17, Ks2, Vs1, Ks0, Vs0, psB, stB, stA, 10)
  WSTEP(18, Ks3, Vs2, Ks1, Vs1, psA, stA, stB, 10)
  WSTEP(19, Ks4, Vs3, Ks2, Vs2, psB, stB, stA, 10)
  WSTEP(20, Ks0, Vs4, Ks3, Vs3, psA, stA, stB, 10)
  WSTEP(21, Ks1, Vs0, Ks4, Vs4, psB, stB, stA, 10)
  WSTEP(22, Ks2, Vs1, Ks0, Vs0, psA, stA, stB, 10)
  WSTEP(23, Ks3, Vs2, Ks1, Vs1, psB, stB, stA, 10)
  WSTEP(24, Ks4, Vs3, Ks2, Vs2, psA, stA, stB, 10)
  WSTEP(25, Ks0, Vs4, Ks3, Vs3, psB, stB, stA, 10)
  WSTEP(26, Ks1, Vs0, Ks4, Vs4, psA, stA, stB, 10)
  WSTEP(27, Ks2, Vs1, Ks0, Vs0, psB, stB, stA, 10)
  WSTEP(28, Ks3, Vs2, Ks1, Vs1, psA, stA, stB, 10)
  WSTEP(29, Ks4, Vs3, Ks0, Vs0, psB, stB, stA, 6)
  WSTEP(30, Ks0, Vs4, Ks0, Vs0, psA, stA, stB, 6)
  WSTEP(31, Ks1, Vs0, Ks0, Vs0, psB, stB, stA, 0)
  WSTEP(32, Ks0, Vs1, Ks0, Vs0, psA, stA, stB, 0)
#undef WSTEP

  const float sc = mask[b * 1024 + q] / l_run;
  f16* ob = attO + ((size_t)b * 1024 + q) * 768 + h * 64;
#pragma unroll
  for (int df = 0; df < 4; ++df) {
    f16x4 o;
#pragma unroll
    for (int r = 0; r < 4; ++r) o[r] = (f16)(acc[df][r] * sc);
    *reinterpret_cast<f16x4*>(ob + df * 16 + grp * 4) = o;
  }
}

extern "C" void kernel_launch(void* const* d_in, const int* in_sizes, int n_in,
                              void* d_out, int out_size, void* d_ws, size_t ws_size,
                              hipStream_t stream) {
  const float* Xq   = (const float*)d_in[0];
  const float* Xkv  = (const float*)d_in[1];
  const float* mask = (const float*)d_in[2];
  const float* Wq   = (const float*)d_in[3];
  const float* bq   = (const float*)d_in[4];
  const float* Wkv  = (const float*)d_in[5];
  const float* bkv  = (const float*)d_in[6];
  const float* Wp   = (const float*)d_in[7];
  const float* bp   = (const float*)d_in[8];
  const float* pos  = (const float*)d_in[9];
  float* out = (float*)d_out;
  char* ws = (char*)d_ws;
  if (ws_size < 42467328) return;  // need ~42.5 MB scratch

  f16* Xq_h  = (f16*)(ws + 0);         // 4096*768
  f16* Xkv_h = (f16*)(ws + 6291456);   // 4096*768
  f16* WqT   = (f16*)(ws + 12582912);  // 768*768
  f16* WkvT  = (f16*)(ws + 13762560);  // 1536*768
  f16* WpT   = (f16*)(ws + 16121856);  // 768*768
  f16* Qb    = (f16*)(ws + 17301504);  // (B,NH,LQ,HD)
  f16* Kb    = (f16*)(ws + 23592960);  // (B,NH,LKV,HD)
  f16* VTb   = (f16*)(ws + 29884416);  // (B,NH,HD,LKV)
  f16* attO  = (f16*)(ws + 36175872);  // (B,LQ,EMBED)

  prep_kernel<<<7296, 256, 0, stream>>>(Xq, Xkv, Wq, Wkv, Wp, Xq_h, Xkv_h, WqT,
                                        WkvT, WpT);
  gemm_qkv_kernel<<<576, 256, 0, stream>>>(Xq_h, WqT, bq, Qb, Xkv_h, WkvT, bkv,
                                           Kb, VTb);
  attn_kernel<<<768, 256, 0, stream>>>(Qb, Kb, VTb, pos, mask, attO);
  gemm_out_kernel<<<192, 256, 0, stream>>>(attO, WpT, bp, out);
}